// Round 2
// baseline (148.109 us; speedup 1.0000x reference)
//
#include <hip/hip_runtime.h>
#include <hip/hip_bf16.h>

// Problem constants (from setup_inputs): B=2, N=2048, E=32768,
// Fin=256, nhead=8, nhid=8 (C1 = 64 concat), Fout=64.
// All float tensors are float32 (per reference); edges int32; output float32.
#define BB   2
#define NN   2048
#define FIN  256
#define HH   8
#define NHID 8
#define C1   64   // HH*NHID
#define FOUT 64

// ---------------------------------------------------------------------------
// K1: h1[b,n,c] = x[b,n,:] @ W_h  (c = head*8+k), fused s1/s2 per head.
// grid = B*N blocks, 64 threads.
__global__ __launch_bounds__(64)
void k_gemm1(const float* __restrict__ x, const float* __restrict__ Wh,
             const float* __restrict__ ah,
             float* __restrict__ h1, float* __restrict__ s1h, float* __restrict__ s2h)
{
    int bn = blockIdx.x;
    int tid = threadIdx.x;
    __shared__ float xs[FIN];
    const float* xr = x + (size_t)bn * FIN;
    for (int i = tid; i < FIN; i += 64) xs[i] = xr[i];
    __syncthreads();

    int head = tid >> 3, k = tid & 7;
    const float* Wp = Wh + head * FIN * NHID + k;
    float acc = 0.f;
    #pragma unroll 8
    for (int f = 0; f < FIN; ++f) acc += xs[f] * Wp[f * NHID];
    h1[(size_t)bn * C1 + tid] = acc;

    float p = acc * ah[head * 16 + k];
    float q = acc * ah[head * 16 + 8 + k];
    for (int o = 1; o < 8; o <<= 1) { p += __shfl_xor(p, o); q += __shfl_xor(q, o); }
    if (k == 0) {
        int b = bn / NN, n = bn % NN;
        s1h[(b * HH + head) * NN + n] = p;
        s2h[(b * HH + head) * NN + n] = q;
    }
}

// ---------------------------------------------------------------------------
// K2: mark unique (src,tgt) pairs via bitmap; count degree of unique edges.
__global__ void k_mark(const int* __restrict__ edges, int E,
                       unsigned* __restrict__ bitmap, int* __restrict__ deg,
                       int* __restrict__ uniq)
{
    int e = blockIdx.x * blockDim.x + threadIdx.x;
    if (e >= E) return;
    int s = edges[e], t = edges[E + e];
    unsigned bit = (unsigned)s * NN + (unsigned)t;
    unsigned m = 1u << (bit & 31);
    unsigned old = atomicOr(&bitmap[bit >> 5], m);
    if (!(old & m)) { uniq[e] = 1; atomicAdd(&deg[s], 1); }
    else            { uniq[e] = 0; }
}

// K3: exclusive scan of deg (N=2048) -> offs[N+1], cursor[N]. One block.
__global__ __launch_bounds__(1024)
void k_scan(const int* __restrict__ deg, int* __restrict__ offs, int* __restrict__ cursor)
{
    __shared__ int sa[NN], sb[NN];
    int tid = threadIdx.x;
    sa[tid] = deg[tid]; sa[tid + 1024] = deg[tid + 1024];
    __syncthreads();
    int* s = sa; int* d = sb;
    for (int off = 1; off < NN; off <<= 1) {
        for (int i = tid; i < NN; i += 1024) {
            int v = s[i];
            if (i >= off) v += s[i - off];
            d[i] = v;
        }
        __syncthreads();
        int* t = s; s = d; d = t;
    }
    // s = inclusive scan
    offs[tid + 1] = s[tid];
    offs[tid + 1025] = s[tid + 1024];
    if (tid == 0) offs[0] = 0;
    cursor[tid] = tid ? s[tid - 1] : 0;
    cursor[tid + 1024] = s[tid + 1023];
}

// K4: scatter unique edges' targets into CSR buckets.
__global__ void k_scatter(const int* __restrict__ edges, int E,
                          const int* __restrict__ uniq, int* __restrict__ cursor,
                          int* __restrict__ csr)
{
    int e = blockIdx.x * blockDim.x + threadIdx.x;
    if (e >= E) return;
    if (uniq[e]) {
        int s = edges[e], t = edges[E + e];
        int pos = atomicAdd(&cursor[s], 1);
        csr[pos] = t;
    }
}

// ---------------------------------------------------------------------------
// K5: layer-1 sparse attention per (b,n); lane = head*8+k. Writes x1 = elu(att@h1 + b_h).
__global__ __launch_bounds__(64)
void k_att1(const float* __restrict__ h1, const float* __restrict__ s1h,
            const float* __restrict__ s2h, const float* __restrict__ bh,
            const int* __restrict__ offs, const int* __restrict__ csr,
             float* __restrict__ x1)
{
    int bn = blockIdx.x;
    int b = bn / NN, n = bn % NN;
    int tid = threadIdx.x, head = tid >> 3;
    int beg = offs[n], end = offs[n + 1];
    const float* hp = h1 + (size_t)b * NN * C1 + tid;
    float out;
    if (beg == end) {
        // row all -1e20 -> uniform softmax over all N targets
        float acc = 0.f;
        for (int j = 0; j < NN; ++j) acc += hp[(size_t)j * C1];
        out = acc * (1.0f / NN);
    } else {
        float s1 = s1h[(b * HH + head) * NN + n];
        const float* s2p = s2h + (b * HH + head) * NN;
        float m = -3.4e38f;
        for (int p = beg; p < end; ++p) {
            int t = csr[p];
            float ee = s1 + s2p[t];
            ee = ee > 0.f ? ee : 0.2f * ee;
            m = fmaxf(m, ee);
        }
        float den = 0.f, acc = 0.f;
        for (int p = beg; p < end; ++p) {
            int t = csr[p];
            float ee = s1 + s2p[t];
            ee = ee > 0.f ? ee : 0.2f * ee;
            float w = expf(ee - m);
            den += w;
            acc += w * hp[(size_t)t * C1];
        }
        out = acc / den;
    }
    out += bh[tid];
    // elu (alpha=1)
    float v = out > 0.f ? out : (expf(out) - 1.f);
    x1[(size_t)bn * C1 + tid] = v;
}

// ---------------------------------------------------------------------------
// K6: h2 = x1 @ W_o, fused s1o/s2o (a_o dots).
__global__ __launch_bounds__(64)
void k_gemm2(const float* __restrict__ x1, const float* __restrict__ Wo,
             const float* __restrict__ ao,
             float* __restrict__ h2, float* __restrict__ s1o, float* __restrict__ s2o)
{
    int bn = blockIdx.x;
    int tid = threadIdx.x;
    __shared__ float xs[C1];
    xs[tid] = x1[(size_t)bn * C1 + tid];
    __syncthreads();
    float acc = 0.f;
    #pragma unroll 16
    for (int f = 0; f < C1; ++f) acc += xs[f] * Wo[f * FOUT + tid];
    h2[(size_t)bn * FOUT + tid] = acc;

    float p = acc * ao[tid];
    float q = acc * ao[FOUT + tid];
    for (int o = 1; o < 64; o <<= 1) { p += __shfl_xor(p, o); q += __shfl_xor(q, o); }
    if (tid == 0) { s1o[bn] = p; s2o[bn] = q; }
}

// K7: layer-2 sparse attention per (b,n); out2 (fp32, pre-logsoftmax).
__global__ __launch_bounds__(64)
void k_att2(const float* __restrict__ h2, const float* __restrict__ s1o,
            const float* __restrict__ s2o, const float* __restrict__ bo,
            const int* __restrict__ offs, const int* __restrict__ csr,
            float* __restrict__ out2)
{
    int bn = blockIdx.x;
    int b = bn / NN, n = bn % NN;
    int tid = threadIdx.x;
    int beg = offs[n], end = offs[n + 1];
    const float* hp = h2 + (size_t)b * NN * FOUT + tid;
    float out;
    if (beg == end) {
        float acc = 0.f;
        for (int j = 0; j < NN; ++j) acc += hp[(size_t)j * FOUT];
        out = acc * (1.0f / NN);
    } else {
        float s1 = s1o[bn];
        const float* s2p = s2o + b * NN;
        float m = -3.4e38f;
        for (int p = beg; p < end; ++p) {
            int t = csr[p];
            float ee = s1 + s2p[t];
            ee = ee > 0.f ? ee : 0.2f * ee;
            m = fmaxf(m, ee);
        }
        float den = 0.f, acc = 0.f;
        for (int p = beg; p < end; ++p) {
            int t = csr[p];
            float ee = s1 + s2p[t];
            ee = ee > 0.f ? ee : 0.2f * ee;
            float w = expf(ee - m);
            den += w;
            acc += w * hp[(size_t)t * FOUT];
        }
        out = acc / den;
    }
    out += bo[tid];
    out2[(size_t)bn * FOUT + tid] = out;
}

// ---------------------------------------------------------------------------
// K8: logsumexp over node axis per (b,o). grid = B*FOUT, 256 threads.
__global__ __launch_bounds__(256)
void k_lse(const float* __restrict__ out2, float* __restrict__ lse)
{
    int b = blockIdx.x >> 6, o = blockIdx.x & 63;
    int tid = threadIdx.x;
    const float* p = out2 + (size_t)b * NN * FOUT + o;
    float m = -3.4e38f;
    for (int n = tid; n < NN; n += 256) m = fmaxf(m, p[(size_t)n * FOUT]);
    for (int off = 1; off < 64; off <<= 1) m = fmaxf(m, __shfl_xor(m, off));
    __shared__ float sm[4];
    __shared__ float ss[4];
    if ((tid & 63) == 0) sm[tid >> 6] = m;
    __syncthreads();
    float M = fmaxf(fmaxf(sm[0], sm[1]), fmaxf(sm[2], sm[3]));
    float s = 0.f;
    for (int n = tid; n < NN; n += 256) s += expf(p[(size_t)n * FOUT] - M);
    for (int off = 1; off < 64; off <<= 1) s += __shfl_xor(s, off);
    if ((tid & 63) == 0) ss[tid >> 6] = s;
    __syncthreads();
    if (tid == 0) lse[blockIdx.x] = M + logf(ss[0] + ss[1] + ss[2] + ss[3]);
}

// K9: final subtract, f32 out.
__global__ __launch_bounds__(256)
void k_final(const float* __restrict__ out2, const float* __restrict__ lse,
             float* __restrict__ out)
{
    int i = blockIdx.x * 256 + threadIdx.x;   // < B*N*FOUT = 262144
    int o = i & 63;
    int b = i >> 17;                          // N*FOUT = 131072 = 2^17
    out[i] = out2[i] - lse[b * 64 + o];
}

// ---------------------------------------------------------------------------
extern "C" void kernel_launch(void* const* d_in, const int* in_sizes, int n_in,
                              void* d_out, int out_size, void* d_ws, size_t ws_size,
                              hipStream_t stream)
{
    (void)n_in; (void)out_size; (void)ws_size;
    const float* x     = (const float*)d_in[0];
    const int*   edges = (const int*)d_in[1];
    const float* Wh    = (const float*)d_in[2];
    const float* ah    = (const float*)d_in[3];
    const float* bh    = (const float*)d_in[4];
    const float* Wo    = (const float*)d_in[5];
    const float* ao    = (const float*)d_in[6];
    const float* bo    = (const float*)d_in[7];
    int E = in_sizes[1] / 2;

    // workspace layout (~5.3 MB total)
    char* w = (char*)d_ws;
    float* h1   = (float*)w; w += (size_t)BB * NN * C1 * 4;     // 1 MB
    float* s1h  = (float*)w; w += (size_t)BB * HH * NN * 4;     // 128 KB
    float* s2h  = (float*)w; w += (size_t)BB * HH * NN * 4;     // 128 KB
    float* x1   = (float*)w; w += (size_t)BB * NN * C1 * 4;     // 1 MB
    float* h2   = (float*)w; w += (size_t)BB * NN * FOUT * 4;   // 1 MB
    float* s1o  = (float*)w; w += (size_t)BB * NN * 4;
    float* s2o  = (float*)w; w += (size_t)BB * NN * 4;
    float* out2 = (float*)w; w += (size_t)BB * NN * FOUT * 4;   // 1 MB
    float* lse  = (float*)w; w += (size_t)BB * FOUT * 4;
    // zero-init region: deg (N ints) + bitmap (N*N/32 words), contiguous
    int*      deg    = (int*)w;      w += (size_t)NN * 4;
    unsigned* bitmap = (unsigned*)w; w += (size_t)NN * NN / 8;  // 512 KB
    int* offs   = (int*)w; w += (size_t)(NN + 1) * 4;
    int* cursor = (int*)w; w += (size_t)NN * 4;
    int* uniq   = (int*)w; w += (size_t)E * 4;
    int* csr    = (int*)w; w += (size_t)E * 4;

    hipMemsetAsync(deg, 0, (size_t)NN * 4 + (size_t)NN * NN / 8, stream);

    k_gemm1<<<BB * NN, 64, 0, stream>>>(x, Wh, ah, h1, s1h, s2h);
    k_mark<<<(E + 255) / 256, 256, 0, stream>>>(edges, E, bitmap, deg, uniq);
    k_scan<<<1, 1024, 0, stream>>>(deg, offs, cursor);
    k_scatter<<<(E + 255) / 256, 256, 0, stream>>>(edges, E, uniq, cursor, csr);
    k_att1<<<BB * NN, 64, 0, stream>>>(h1, s1h, s2h, bh, offs, csr, x1);
    k_gemm2<<<BB * NN, 64, 0, stream>>>(x1, Wo, ao, h2, s1o, s2o);
    k_att2<<<BB * NN, 64, 0, stream>>>(h2, s1o, s2o, bo, offs, csr, out2);
    k_lse<<<BB * FOUT, 256, 0, stream>>>(out2, lse);
    k_final<<<(BB * NN * FOUT) / 256, 256, 0, stream>>>(out2, lse, (float*)d_out);
}